// Round 11
// baseline (222.817 us; speedup 1.0000x reference)
//
#include <hip/hip_runtime.h>
#include <hip/hip_bf16.h>

// Problem dims
constexpr int B   = 2;
constexpr int HH  = 7;    // history turns
constexpr int H   = 8;    // total turns
constexpr int L   = 256;
constexpr int C   = 512;
constexpr int NH  = 8;
constexpr int DH  = 64;
constexpr int KS  = 4;    // top-k slots
constexpr int BH  = B * H;          // 16
constexpr int M4  = B * H * L;      // 4096 rows
constexpr size_t S = (size_t)B * H * L * C;  // 2,097,152 elems

typedef __attribute__((ext_vector_type(8))) short short8;
typedef __attribute__((ext_vector_type(4))) float f32x4;
typedef unsigned short u16;
typedef unsigned int u32;

__device__ inline float bf2f(u16 u) {
    u32 x = ((u32)u) << 16;
    return __uint_as_float(x);
}
__device__ inline u16 f2bf(float f) {
    __hip_bfloat16 h = __float2bfloat16(f);
    return *reinterpret_cast<u16*>(&h);
}
__device__ inline u32 packbf(float lo, float hi) {
    return ((u32)f2bf(hi) << 16) | (u32)f2bf(lo);
}
__device__ inline void gload16(const void* g, void* l) {
    __builtin_amdgcn_global_load_lds(
        (const __attribute__((address_space(1))) void*)g,
        (__attribute__((address_space(3))) void*)l,
        16, 0, 0);
}
__device__ inline void vmcnt0() {
    asm volatile("s_waitcnt vmcnt(0)" ::: "memory");
}
__device__ inline void vmcnt3() {
    asm volatile("s_waitcnt vmcnt(3)" ::: "memory");
}
__device__ inline void vmcnt4() {
    asm volatile("s_waitcnt vmcnt(4)" ::: "memory");
}

// ------------------------------------------------- concat ctx (+bf16 cast)
__global__ __launch_bounds__(256) void concat_cast_kernel(
    const float* __restrict__ hist, const float* __restrict__ cur,
    float* __restrict__ ctx, u16* __restrict__ Xb)
{
    size_t i4 = (size_t)blockIdx.x * 256 + threadIdx.x;
    size_t elem = i4 * 4;
    int c  = (int)(elem & (C - 1));
    size_t rest = elem >> 9;
    int l  = (int)(rest & (L - 1));
    int bh = (int)(rest >> 8);
    int h  = bh & (H - 1);
    int b  = bh >> 3;
    float4 v;
    if (h < HH) {
        size_t off = ((((size_t)b * HH + h) * L + l) * C + c);
        v = *reinterpret_cast<const float4*>(hist + off);
    } else {
        size_t off = (((size_t)b * L + l) * C + c);
        v = *reinterpret_cast<const float4*>(cur + off);
    }
    *reinterpret_cast<float4*>(ctx + elem) = v;
    ushort4 o;
    o.x = f2bf(v.x); o.y = f2bf(v.y); o.z = f2bf(v.z); o.w = f2bf(v.w);
    *reinterpret_cast<ushort4*>(Xb + elem) = o;
}

// ---------------------------------------------------------------- topk+softmax
__global__ void topk_kernel(const float* __restrict__ gmap,
                            float* __restrict__ attnw,
                            int* __restrict__ indxO,
                            int* __restrict__ expertO)
{
    int t = threadIdx.x;
    if (t >= BH) return;
    int h = t & (H - 1);
    const float* row = gmap + (size_t)t * H;
    float v[H];
    #pragma unroll
    for (int j = 0; j < H; ++j) v[j] = row[j];
    float sel[KS]; int si[KS];
    #pragma unroll
    for (int kk = 0; kk < KS; ++kk) {
        float best = -1e30f; int bi = 0;
        #pragma unroll
        for (int j = 0; j < H; ++j) {
            if (v[j] > best) { best = v[j]; bi = j; }
        }
        sel[kk] = best; si[kk] = bi; v[bi] = -1e30f;
    }
    float mx = sel[0];
    float w[KS]; float sum = 0.f;
    #pragma unroll
    for (int kk = 0; kk < KS; ++kk) { w[kk] = __expf(sel[kk] - mx); sum += w[kk]; }
    float inv = 1.f / sum;
    #pragma unroll
    for (int kk = 0; kk < KS; ++kk) {
        attnw[t * KS + kk] = w[kk] * inv;
        indxO[t * KS + kk] = si[kk];
        int e = (si[kk] == h) ? 0 : ((si[kk] > h) ? 2 : 1);
        expertO[t * KS + kk] = e;
    }
}

// ---------------------------------------------------------------- combined bias
__global__ __launch_bounds__(256) void biasc_kernel(
    const float* __restrict__ bo,
    const float* __restrict__ attnw, const int* __restrict__ expertArr,
    float* __restrict__ biasC)
{
    int bh = blockIdx.x;
    float a[KS]; int e[KS];
    #pragma unroll
    for (int k = 0; k < KS; ++k) {
        a[k] = attnw[bh * KS + k];
        e[k] = expertArr[bh * KS + k];
    }
    #pragma unroll
    for (int it = 0; it < 2; ++it) {
        int c = threadIdx.x + it * 256;
        float s = 0.f;
        #pragma unroll
        for (int k = 0; k < KS; ++k)
            s += a[k] * bo[(size_t)e[k] * C + c];
        biasC[(size_t)bh * C + c] = s;
    }
}

// ---------------------------------------------------------------- weight casts
__global__ __launch_bounds__(256) void cast_w_kernel(
    const float* __restrict__ Wq, const float* __restrict__ Wk,
    const float* __restrict__ Wv, u16* __restrict__ Wt)
{
    int p = blockIdx.z;
    int e = p / 3, t = p % 3;
    const float* W = (t == 0 ? Wq : (t == 1 ? Wk : Wv)) + (size_t)e * C * C;
    __shared__ float tile[32][33];
    int k0 = blockIdx.y * 32, n0 = blockIdx.x * 32;
    int tc = threadIdx.x & 31, tr = threadIdx.x >> 5;
    #pragma unroll
    for (int i = 0; i < 4; ++i) {
        int r = tr + i * 8;
        tile[r][tc] = W[(size_t)(k0 + r) * C + n0 + tc];
    }
    __syncthreads();
    #pragma unroll
    for (int i = 0; i < 4; ++i) {
        int r = tr + i * 8;
        Wt[(size_t)p * C * C + (size_t)(n0 + r) * C + k0 + tc] = f2bf(tile[tc][r]);
    }
}

__global__ __launch_bounds__(256) void cast_wo_kernel(
    const float* __restrict__ Wo, u16* __restrict__ Wot)
{
    int p = blockIdx.z;
    const float* W = Wo + (size_t)p * C * C;
    __shared__ float tile[32][33];
    int k0 = blockIdx.y * 32, n0 = blockIdx.x * 32;
    int tc = threadIdx.x & 31, tr = threadIdx.x >> 5;
    #pragma unroll
    for (int i = 0; i < 4; ++i) {
        int r = tr + i * 8;
        tile[r][tc] = W[(size_t)(k0 + r) * C + n0 + tc];
    }
    __syncthreads();
    #pragma unroll
    for (int i = 0; i < 4; ++i) {
        int r = tr + i * 8;
        Wot[(size_t)p * C * C + (size_t)(n0 + r) * C + k0 + tc] = f2bf(tile[tc][r]);
    }
}

// ---------------------------------------------------------------- QKV proj MFMA
// 128x256 tile, 512 threads (8 waves = 2 wr x 4 wc, 64x64 each); BK=32 dbuf,
// counted vmcnt(3); swapped-operand mfma -> uint2 coalesced epilogue.
// Grid 576 blocks = 2.25/CU, 48KB LDS -> fully co-resident (single round).
__global__ __launch_bounds__(512) void proj_mfma(
    const u16* __restrict__ Xb, const u16* __restrict__ Wt,
    const float* __restrict__ bq, const float* __restrict__ bk,
    const float* __restrict__ bv,
    u16* __restrict__ out)
{
    constexpr int BK = 32;
    constexpr int NT = C / BK;   // 16
    int p = blockIdx.z;
    int e = p / 3, t = p % 3;
    const float* bias = (t == 0 ? bq : (t == 1 ? bk : bv)) + (size_t)e * C;
    u16* Y = out + (size_t)p * S;
    const u16* Wp = Wt + (size_t)p * C * C;

    int m0 = blockIdx.y * 128;
    int n0 = blockIdx.x * 256;

    __shared__ u16 As[2][128 * BK];   // 2 x 8KB
    __shared__ u16 Bs[2][256 * BK];   // 2 x 16KB

    int tid  = threadIdx.x;
    int lane = tid & 63;
    int wid  = tid >> 6;              // 0..7
    int wr = wid >> 2, wc = wid & 3;  // 2 x 4 waves
    int c = lane & 15, gl = lane >> 4;

    f32x4 acc[4][4];   // [nblk][mblk]
    #pragma unroll
    for (int n = 0; n < 4; ++n)
        #pragma unroll
        for (int m = 0; m < 4; ++m)
            acc[n][m] = (f32x4){0.f, 0.f, 0.f, 0.f};

    int rowA = wr * 64 + c;
    int rowB = wc * 64 + c;

    auto stage = [&](int bb, int kt) {
        int k0 = kt * BK;
        // A: 512 chunks of 16B, 1/thread
        {
            int base = wid * 64;
            int ch = base + lane;
            int r = ch >> 2, s = ch & 3;
            int r_src = r ^ ((r >> 2) & 1);
            int s_src = s ^ (r_src & 3);
            gload16(Xb + (size_t)(m0 + r_src) * C + k0 + s_src * 8,
                    &As[bb][base * 8]);
        }
        // B: 1024 chunks, 2/thread
        #pragma unroll
        for (int it = 0; it < 2; ++it) {
            int base = it * 512 + wid * 64;
            int ch = base + lane;
            int r = ch >> 2, s = ch & 3;
            int r_src = r ^ ((r >> 2) & 1);
            int s_src = s ^ (r_src & 3);
            gload16(Wp + (size_t)(n0 + r_src) * C + k0 + s_src * 8,
                    &Bs[bb][base * 8]);
        }
    };

    stage(0, 0);

    for (int kt = 0; kt < NT; ++kt) {
        int bb = kt & 1;
        if (kt + 1 < NT) {
            stage(bb ^ 1, kt + 1);   // 3 loads -> stay in flight across barriers
            vmcnt3();                // wait only for tile kt's 3 loads
        } else {
            vmcnt0();
        }
        __syncthreads();
        const char* Ab = (const char*)&As[bb][0];
        const char* Bb = (const char*)&Bs[bb][0];
        short8 af[4], bfr[4];
        #pragma unroll
        for (int m = 0; m < 4; ++m) {
            int row = rowA + m * 16;
            af[m] = *reinterpret_cast<const short8*>(
                Ab + ((row * 64 + gl * 16) ^ ((row & 7) << 4)));
        }
        #pragma unroll
        for (int n = 0; n < 4; ++n) {
            int row = rowB + n * 16;
            bfr[n] = *reinterpret_cast<const short8*>(
                Bb + ((row * 64 + gl * 16) ^ ((row & 7) << 4)));
        }
        #pragma unroll
        for (int n = 0; n < 4; ++n)
            #pragma unroll
            for (int m = 0; m < 4; ++m)
                acc[n][m] = __builtin_amdgcn_mfma_f32_16x16x32_bf16(
                    bfr[n], af[m], acc[n][m], 0, 0, 0);
        if (kt + 1 < NT) __syncthreads();   // seal reads before next stage overwrites
    }

    // epilogue: row = m0+wr*64+m*16+c; col = n0+wc*64+n*16+gl*4+r  (uint2)
    int mrow = m0 + wr * 64 + c;
    int colb = n0 + wc * 64 + gl * 4;
    #pragma unroll
    for (int n = 0; n < 4; ++n) {
        int col = colb + n * 16;
        float4 b4 = *reinterpret_cast<const float4*>(&bias[col]);
        #pragma unroll
        for (int m = 0; m < 4; ++m) {
            int row = mrow + m * 16;
            uint2 v;
            v.x = packbf(acc[n][m][0] + b4.x, acc[n][m][1] + b4.y);
            v.y = packbf(acc[n][m][2] + b4.z, acc[n][m][3] + b4.w);
            *reinterpret_cast<uint2*>(&Y[(size_t)row * C + col]) = v;
        }
    }
}

// ---------------------------------------------------------------- MFMA flash attention
__global__ __launch_bounds__(256) void attn_mfma(
    const u16* __restrict__ qkv,
    const int* __restrict__ indx, const int* __restrict__ expertArr,
    const float* __restrict__ attnw,
    u16* __restrict__ Obuf)
{
    int head = blockIdx.x;
    int slot = blockIdx.y;
    int z    = blockIdx.z;
    int bh   = z >> 1, qh = z & 1;
    int b    = bh >> 3;
    int mi   = bh * KS + slot;
    int src  = indx[mi];
    int e    = expertArr[mi];
    float ak = attnw[mi];
    int qbase = qh * 128;

    const u16* qp = qkv + (size_t)(e * 3 + 0) * S + (size_t)bh * L * C + head * DH;
    const u16* kp = qkv + (size_t)(e * 3 + 1) * S + (size_t)(b * H + src) * L * C + head * DH;
    const u16* vp = qkv + (size_t)(e * 3 + 2) * S + (size_t)(b * H + src) * L * C + head * DH;

    __shared__ u16 Ks[64 * 64];
    __shared__ u16 Vt[64 * 64];
    __shared__ u16 Pl[4][32 * 64];

    int tid = threadIdx.x, lane = tid & 63, w = tid >> 6;
    int c = lane & 15, gl = lane >> 4;
    int qoff = qbase + w * 32;

    short8 qf[2][2];
    #pragma unroll
    for (int n = 0; n < 2; ++n)
        #pragma unroll
        for (int kf = 0; kf < 2; ++kf)
            qf[n][kf] = *reinterpret_cast<const short8*>(
                qp + (size_t)(qoff + n * 16 + c) * C + kf * 32 + 8 * gl);

    f32x4 accO[4][2];
    #pragma unroll
    for (int m = 0; m < 4; ++m)
        #pragma unroll
        for (int n = 0; n < 2; ++n)
            accO[m][n] = (f32x4){0.f, 0.f, 0.f, 0.f};
    float mrun[2], lrun[2];
    #pragma unroll
    for (int n = 0; n < 2; ++n) { mrun[n] = -1e30f; lrun[n] = 0.f; }

    char* Plw = (char*)&Pl[w][0];

    for (int t = 0; t < 4; ++t) {
        int c0 = t * 64;
        __syncthreads();
        #pragma unroll
        for (int it = 0; it < 2; ++it) {
            int ch = tid + 256 * it;
            int r = ch >> 3, cb = ch & 7;
            short8 kv = *reinterpret_cast<const short8*>(kp + (size_t)(c0 + r) * C + cb * 8);
            int ad = (r * 128 + cb * 16) ^ ((r & 7) << 4);
            *reinterpret_cast<short8*>((char*)Ks + ad) = kv;
        }
        {
            int rp = tid & 31;
            int d0 = (tid >> 5) * 8;
            const u16* v0p = vp + (size_t)(c0 + 2 * rp) * C + d0;
            const u16* v1p = v0p + C;
            ushort4 a0 = *reinterpret_cast<const ushort4*>(v0p);
            ushort4 a1 = *reinterpret_cast<const ushort4*>(v0p + 4);
            ushort4 b0 = *reinterpret_cast<const ushort4*>(v1p);
            ushort4 b1 = *reinterpret_cast<const ushort4*>(v1p + 4);
            u16 va[8] = {a0.x, a0.y, a0.z, a0.w, a1.x, a1.y, a1.z, a1.w};
            u16 vb[8] = {b0.x, b0.y, b0.z, b0.w, b1.x, b1.y, b1.z, b1.w};
            #pragma unroll
            for (int j = 0; j < 8; ++j) {
                u32 pk = ((u32)vb[j] << 16) | (u32)va[j];
                int ad = ((d0 + j) * 128 + rp * 4) ^ (((d0 + j) & 7) << 4);
                *reinterpret_cast<u32*>((char*)Vt + ad) = pk;
            }
        }
        __syncthreads();

        f32x4 accS[4][2];
        #pragma unroll
        for (int m = 0; m < 4; ++m)
            #pragma unroll
            for (int n = 0; n < 2; ++n)
                accS[m][n] = (f32x4){0.f, 0.f, 0.f, 0.f};
        #pragma unroll
        for (int kf = 0; kf < 2; ++kf) {
            short8 ka[4];
            #pragma unroll
            for (int m = 0; m < 4; ++m) {
                int row = m * 16 + c;
                ka[m] = *reinterpret_cast<const short8*>(
                    (char*)Ks + ((row * 128 + (kf * 32 + 8 * gl) * 2) ^ ((row & 7) << 4)));
            }
            #pragma unroll
            for (int m = 0; m < 4; ++m)
                #pragma unroll
                for (int n = 0; n < 2; ++n)
                    accS[m][n] = __builtin_amdgcn_mfma_f32_16x16x32_bf16(
                        ka[m], qf[n][kf], accS[m][n], 0, 0, 0);
        }

        #pragma unroll
        for (int n = 0; n < 2; ++n) {
            float tm = -1e30f;
            #pragma unroll
            for (int m = 0; m < 4; ++m)
                #pragma unroll
                for (int r = 0; r < 4; ++r)
                    tm = fmaxf(tm, accS[m][n][r] * 0.125f);
            tm = fmaxf(tm, __shfl_xor(tm, 16));
            tm = fmaxf(tm, __shfl_xor(tm, 32));
            float nm = fmaxf(mrun[n], tm);
            float al = __expf(mrun[n] - nm);
            mrun[n] = nm;
            lrun[n] *= al;
            #pragma unroll
            for (int m = 0; m < 4; ++m)
                #pragma unroll
                for (int r = 0; r < 4; ++r)
                    accO[m][n][r] *= al;
            float ps = 0.f;
            #pragma unroll
            for (int m = 0; m < 4; ++m)
                #pragma unroll
                for (int r = 0; r < 4; ++r) {
                    float pv = __expf(accS[m][n][r] * 0.125f - nm);
                    accS[m][n][r] = pv;
                    ps += pv;
                }
            lrun[n] += ps;
            int row = n * 16 + c;
            int sw = (row & 7) << 4;
            #pragma unroll
            for (int m = 0; m < 4; ++m) {
                u32 p0 = packbf(accS[m][n][0], accS[m][n][1]);
                u32 p1 = packbf(accS[m][n][2], accS[m][n][3]);
                int base = row * 128 + (m * 16 + 4 * gl) * 2;
                *reinterpret_cast<u32*>(Plw + (base ^ sw)) = p0;
                *reinterpret_cast<u32*>(Plw + ((base + 4) ^ sw)) = p1;
            }
        }

        #pragma unroll
        for (int kf = 0; kf < 2; ++kf) {
            short8 va[4], pb[2];
            #pragma unroll
            for (int m = 0; m < 4; ++m) {
                int row = m * 16 + c;
                va[m] = *reinterpret_cast<const short8*>(
                    (char*)Vt + ((row * 128 + (kf * 32 + 8 * gl) * 2) ^ ((row & 7) << 4)));
            }
            #pragma unroll
            for (int n = 0; n < 2; ++n) {
                int row = n * 16 + c;
                pb[n] = *reinterpret_cast<const short8*>(
                    Plw + ((row * 128 + (kf * 32 + 8 * gl) * 2) ^ ((row & 7) << 4)));
            }
            #pragma unroll
            for (int m = 0; m < 4; ++m)
                #pragma unroll
                for (int n = 0; n < 2; ++n)
                    accO[m][n] = __builtin_amdgcn_mfma_f32_16x16x32_bf16(
                        va[m], pb[n], accO[m][n], 0, 0, 0);
        }
    }

    float inv[2];
    #pragma unroll
    for (int n = 0; n < 2; ++n) {
        float lv = lrun[n];
        lv += __shfl_xor(lv, 16);
        lv += __shfl_xor(lv, 32);
        inv[n] = ak / lv;     // fold a_k into O
    }
    #pragma unroll
    for (int m = 0; m < 4; ++m)
        #pragma unroll
        for (int n = 0; n < 2; ++n) {
            int row = n * 16 + c;
            int sw = (row & 7) << 4;
            float o0 = accO[m][n][0] * inv[n];
            float o1 = accO[m][n][1] * inv[n];
            float o2 = accO[m][n][2] * inv[n];
            float o3 = accO[m][n][3] * inv[n];
            int base = row * 128 + (m * 16 + 4 * gl) * 2;
            *reinterpret_cast<u32*>(Plw + (base ^ sw)) = packbf(o0, o1);
            *reinterpret_cast<u32*>(Plw + ((base + 4) ^ sw)) = packbf(o2, o3);
        }
    #pragma unroll
    for (int it = 0; it < 4; ++it) {
        int q = it * 8 + (lane >> 3), cb = lane & 7;
        short8 ov = *reinterpret_cast<const short8*>(
            Plw + ((q * 128 + cb * 16) ^ ((q & 7) << 4)));
        *reinterpret_cast<short8*>(
            Obuf + ((size_t)mi * L + qoff + q) * C + head * DH + cb * 8) = ov;
    }
}

// ---------------------------------------------------------------- Wo fused-K GEMM + ew epilogue
// R10 structure: XCD remap, counted vmcnt(4), swapped-operand mfma,
// float4/uint2 coalesced epilogue.
__global__ __launch_bounds__(256) void wo_fused_ew(
    const u16* __restrict__ Obuf, const u16* __restrict__ Wot,
    const int* __restrict__ expertArr, const float* __restrict__ biasC,
    const float* __restrict__ xin,
    float* __restrict__ xout, u16* __restrict__ XbOut)
{
    constexpr int BK = 64;
    int bid  = blockIdx.x;             // 0..511
    int xcd  = bid & 7;
    int slot = bid >> 3;               // 0..63
    int gwi  = xcd * 64 + slot;
    int bh   = gwi >> 5;
    int wp   = gwi & 31;
    int n0   = (wp & 7) * 64;
    int m0   = (wp >> 3) * 64;

    int e4[KS];
    #pragma unroll
    for (int k = 0; k < KS; ++k) e4[k] = expertArr[bh * KS + k];

    __shared__ u16 As[2][64 * BK];    // 2 x 8KB
    __shared__ u16 Bs[2][64 * BK];    // 2 x 8KB

    int tid = threadIdx.x, lane = tid & 63, wid = tid >> 6;
    int wr = wid >> 1, wc = wid & 1;   // 2x2 waves of 32x32
    int c = lane & 15, gl = lane >> 4;

    f32x4 acc[2][2];   // [nblk][mblk]
    #pragma unroll
    for (int n = 0; n < 2; ++n)
        #pragma unroll
        for (int m = 0; m < 2; ++m)
            acc[n][m] = (f32x4){0.f, 0.f, 0.f, 0.f};

    auto stage = [&](int bb, int kt) {
        int kslot = kt >> 3;
        int k0    = (kt & 7) * BK;
        const u16* Ap = Obuf + ((size_t)(bh * KS + kslot) * L + m0) * C + k0;
        const u16* Bp = Wot + (size_t)e4[kslot] * C * C + (size_t)n0 * C + k0;
        #pragma unroll
        for (int it = 0; it < 2; ++it) {
            int base = wid * 64 + it * 256;
            int ch = base + lane;
            int r = ch >> 3, cb = ch & 7;
            int ksw = (cb ^ (r & 7)) << 3;
            gload16(Ap + (size_t)r * C + ksw, &As[bb][base * 8]);
        }
        #pragma unroll
        for (int it = 0; it < 2; ++it) {
            int base = wid * 64 + it * 256;
            int ch = base + lane;
            int r = ch >> 3, cb = ch & 7;
            int ksw = (cb ^ (r & 7)) << 3;
            gload16(Bp + (size_t)r * C + ksw, &Bs[bb][base * 8]);
        }
    };

    stage(0, 0);

    constexpr int NT = 4 * (C / BK);   // 32 k-tiles
    for (int kt = 0; kt < NT; ++kt) {
        int bb = kt & 1;
        if (kt + 1 < NT) {
            stage(bb ^ 1, kt + 1);
            vmcnt4();                // wait for tile kt only
        } else {
            vmcnt0();
        }
        __syncthreads();
        const char* Ab = (const char*)&As[bb][0];
        const char* Bb = (const char*)&Bs[bb][0];
        #pragma unroll
        for (int ks = 0; ks < 2; ++ks) {
            int kb2 = (ks * 32 + 8 * gl) * 2;
            short8 af[2], bfr[2];
            #pragma unroll
            for (int m = 0; m < 2; ++m) {
                int row = wr * 32 + m * 16 + c;
                af[m] = *reinterpret_cast<const short8*>(
                    Ab + ((row * 128 + kb2) ^ ((row & 7) << 4)));
            }
            #pragma unroll
            for (int n = 0; n < 2; ++n) {
                int row = wc * 32 + n * 16 + c;
                bfr[n] = *reinterpret_cast<const short8*>(
                    Bb + ((row * 128 + kb2) ^ ((row & 7) << 4)));
            }
            #pragma unroll
            for (int n = 0; n < 2; ++n)
                #pragma unroll
                for (int m = 0; m < 2; ++m)
                    acc[n][m] = __builtin_amdgcn_mfma_f32_16x16x32_bf16(
                        bfr[n], af[m], acc[n][m], 0, 0, 0);
        }
        if (kt + 1 < NT) __syncthreads();
    }

    // ---- fused epilogue: +biasC, relu, +residual; float4/uint2 stores
    const float* xr = xin + (size_t)bh * L * C;
    float* xo = xout + (size_t)bh * L * C;
    u16*   xb = XbOut + (size_t)bh * L * C;
    int mrow = m0 + wr * 32 + c;
    int colb = n0 + wc * 32 + gl * 4;
    #pragma unroll
    for (int n = 0; n < 2; ++n) {
        int col = colb + n * 16;
        float4 b4 = *reinterpret_cast<const float4*>(&biasC[(size_t)bh * C + col]);
        #pragma unroll
        for (int m = 0; m < 2; ++m) {
            int row = mrow + m * 16;
            float4 x4 = *reinterpret_cast<const float4*>(&xr[(size_t)row * C + col]);
            float o0 = fmaxf(acc[n][m][0] + b4.x, 0.f) + x4.x;
            float o1 = fmaxf(acc[n][m][1] + b4.y, 0.f) + x4.y;
            float o2 = fmaxf(acc[n][m][2] + b4.z, 0.f) + x4.z;
            float o3 = fmaxf(acc[n][m][3] + b4.w, 0.f) + x4.w;
            float4 ov; ov.x = o0; ov.y = o1; ov.z = o2; ov.w = o3;
            *reinterpret_cast<float4*>(&xo[(size_t)row * C + col]) = ov;
            uint2 pv;
            pv.x = packbf(o0, o1);
            pv.y = packbf(o2, o3);
            *reinterpret_cast<uint2*>(&xb[(size_t)row * C + col]) = pv;
        }
    }
}

// ----------------------------------------------------------------------------
extern "C" void kernel_launch(void* const* d_in, const int* in_sizes, int n_in,
                              void* d_out, int out_size, void* d_ws, size_t ws_size,
                              hipStream_t stream) {
    const float* gmap = (const float*)d_in[0];
    const float* hist = (const float*)d_in[1];
    const float* cur  = (const float*)d_in[2];
    const float* Wq   = (const float*)d_in[6];
    const float* bq   = (const float*)d_in[7];
    const float* Wk   = (const float*)d_in[8];
    const float* bk   = (const float*)d_in[9];
    const float* Wv   = (const float*)d_in[10];
    const float* bv   = (const float*)d_in[11];
    const float* Wo   = (const float*)d_in[12];
    const float* bo   = (const float*)d_in[13];
    float* outp       = (float*)d_out;

    char* ws = (char*)d_ws;
    float* ctx  = (float*)(ws);                      // [0,4S)
    float* x1   = (float*)(ws + 4 * S);              // [4S,8S)
    u16*   qkv  = (u16*)(ws + 12 * S);               // [12S,30S)
    u16*   Obuf = (u16*)(ws + 30 * S);               // [30S,38S)
    char*  tail = ws + 38 * S;
    float* attnw  = (float*)(tail);                  // 256 B
    int*   indx   = (int*)(tail + 256);
    int*   expert = (int*)(tail + 512);
    float* biasC  = (float*)(tail + 1024);           // 32 KB
    u16*   Wot    = (u16*)(tail + 64 * 1024);        // 1.57 MB
    u16*   Xb     = (u16*)(tail + 2 * 1024 * 1024);  // 4 MB
    u16*   Wt     = (u16*)(tail + 8 * 1024 * 1024);  // 4.7 MB

    dim3 projGrid(C / 256, M4 / 128, 9);             // 2 x 32 x 9 = 576
    dim3 castWGrid(C / 32, C / 32, 9);
    dim3 castWoGrid(C / 32, C / 32, 3);
    dim3 attnGrid(NH, KS, BH * 2);
    int woBlocks = (C / 64) * (L / 64) * BH;         // 512, flat + remap
    int ewBlocks = (int)(S / 4 / 256);   // 2048

    concat_cast_kernel<<<ewBlocks, 256, 0, stream>>>(hist, cur, ctx, Xb);
    topk_kernel<<<1, 64, 0, stream>>>(gmap, attnw, indx, expert);
    biasc_kernel<<<BH, 256, 0, stream>>>(bo, attnw, expert, biasC);
    cast_wo_kernel<<<castWoGrid, 256, 0, stream>>>(Wo, Wot);
    cast_w_kernel<<<castWGrid, 256, 0, stream>>>(Wq, Wk, Wv, Wt);

    // ---- layer 1: ctx -> x1 (+Xb for layer-2 proj)
    proj_mfma<<<projGrid, 512, 0, stream>>>(Xb, Wt, bq, bk, bv, qkv);
    attn_mfma<<<attnGrid, 256, 0, stream>>>(qkv, indx, expert, attnw, Obuf);
    wo_fused_ew<<<woBlocks, 256, 0, stream>>>(Obuf, Wot, expert, biasC, ctx, x1, Xb);

    // ---- layer 2: x1 -> out
    proj_mfma<<<projGrid, 512, 0, stream>>>(Xb, Wt, bq, bk, bv, qkv);
    attn_mfma<<<attnGrid, 256, 0, stream>>>(qkv, indx, expert, attnw, Obuf);
    wo_fused_ew<<<woBlocks, 256, 0, stream>>>(Obuf, Wot, expert, biasC, x1, outp, Xb);
}

// Round 12
// 179.103 us; speedup vs baseline: 1.2441x; 1.2441x over previous
//
#include <hip/hip_runtime.h>
#include <hip/hip_bf16.h>

// Problem dims
constexpr int B   = 2;
constexpr int HH  = 7;    // history turns
constexpr int H   = 8;    // total turns
constexpr int L   = 256;
constexpr int C   = 512;
constexpr int NH  = 8;
constexpr int DH  = 64;
constexpr int KS  = 4;    // top-k slots
constexpr int BH  = B * H;          // 16
constexpr int M4  = B * H * L;      // 4096 rows
constexpr size_t S = (size_t)B * H * L * C;  // 2,097,152 elems

typedef __attribute__((ext_vector_type(8))) short short8;
typedef __attribute__((ext_vector_type(4))) float f32x4;
typedef unsigned short u16;
typedef unsigned int u32;

__device__ inline float bf2f(u16 u) {
    u32 x = ((u32)u) << 16;
    return __uint_as_float(x);
}
__device__ inline u16 f2bf(float f) {
    __hip_bfloat16 h = __float2bfloat16(f);
    return *reinterpret_cast<u16*>(&h);
}
__device__ inline u32 packbf(float lo, float hi) {
    return ((u32)f2bf(hi) << 16) | (u32)f2bf(lo);
}
__device__ inline void gload16(const void* g, void* l) {
    __builtin_amdgcn_global_load_lds(
        (const __attribute__((address_space(1))) void*)g,
        (__attribute__((address_space(3))) void*)l,
        16, 0, 0);
}
__device__ inline void vmcnt0() { asm volatile("s_waitcnt vmcnt(0)" ::: "memory"); }
__device__ inline void vmcnt4() { asm volatile("s_waitcnt vmcnt(4)" ::: "memory"); }
__device__ inline void vmcnt8() { asm volatile("s_waitcnt vmcnt(8)" ::: "memory"); }

// ------------------------------------------------- concat ctx (+bf16 cast)
__global__ __launch_bounds__(256) void concat_cast_kernel(
    const float* __restrict__ hist, const float* __restrict__ cur,
    float* __restrict__ ctx, u16* __restrict__ Xb)
{
    size_t i4 = (size_t)blockIdx.x * 256 + threadIdx.x;
    size_t elem = i4 * 4;
    int c  = (int)(elem & (C - 1));
    size_t rest = elem >> 9;
    int l  = (int)(rest & (L - 1));
    int bh = (int)(rest >> 8);
    int h  = bh & (H - 1);
    int b  = bh >> 3;
    float4 v;
    if (h < HH) {
        size_t off = ((((size_t)b * HH + h) * L + l) * C + c);
        v = *reinterpret_cast<const float4*>(hist + off);
    } else {
        size_t off = (((size_t)b * L + l) * C + c);
        v = *reinterpret_cast<const float4*>(cur + off);
    }
    *reinterpret_cast<float4*>(ctx + elem) = v;
    ushort4 o;
    o.x = f2bf(v.x); o.y = f2bf(v.y); o.z = f2bf(v.z); o.w = f2bf(v.w);
    *reinterpret_cast<ushort4*>(Xb + elem) = o;
}

// ---------------------------------------------------------------- topk+softmax
__global__ void topk_kernel(const float* __restrict__ gmap,
                            float* __restrict__ attnw,
                            int* __restrict__ indxO,
                            int* __restrict__ expertO)
{
    int t = threadIdx.x;
    if (t >= BH) return;
    int h = t & (H - 1);
    const float* row = gmap + (size_t)t * H;
    float v[H];
    #pragma unroll
    for (int j = 0; j < H; ++j) v[j] = row[j];
    float sel[KS]; int si[KS];
    #pragma unroll
    for (int kk = 0; kk < KS; ++kk) {
        float best = -1e30f; int bi = 0;
        #pragma unroll
        for (int j = 0; j < H; ++j) {
            if (v[j] > best) { best = v[j]; bi = j; }
        }
        sel[kk] = best; si[kk] = bi; v[bi] = -1e30f;
    }
    float mx = sel[0];
    float w[KS]; float sum = 0.f;
    #pragma unroll
    for (int kk = 0; kk < KS; ++kk) { w[kk] = __expf(sel[kk] - mx); sum += w[kk]; }
    float inv = 1.f / sum;
    #pragma unroll
    for (int kk = 0; kk < KS; ++kk) {
        attnw[t * KS + kk] = w[kk] * inv;
        indxO[t * KS + kk] = si[kk];
        int e = (si[kk] == h) ? 0 : ((si[kk] > h) ? 2 : 1);
        expertO[t * KS + kk] = e;
    }
}

// ---------------------------------------------------------------- combined bias
__global__ __launch_bounds__(256) void biasc_kernel(
    const float* __restrict__ bo,
    const float* __restrict__ attnw, const int* __restrict__ expertArr,
    float* __restrict__ biasC)
{
    int bh = blockIdx.x;
    float a[KS]; int e[KS];
    #pragma unroll
    for (int k = 0; k < KS; ++k) {
        a[k] = attnw[bh * KS + k];
        e[k] = expertArr[bh * KS + k];
    }
    #pragma unroll
    for (int it = 0; it < 2; ++it) {
        int c = threadIdx.x + it * 256;
        float s = 0.f;
        #pragma unroll
        for (int k = 0; k < KS; ++k)
            s += a[k] * bo[(size_t)e[k] * C + c];
        biasC[(size_t)bh * C + c] = s;
    }
}

// ---------------------------------------------------------------- weight casts
__global__ __launch_bounds__(256) void cast_w_kernel(
    const float* __restrict__ Wq, const float* __restrict__ Wk,
    const float* __restrict__ Wv, u16* __restrict__ Wt)
{
    int p = blockIdx.z;
    int e = p / 3, t = p % 3;
    const float* W = (t == 0 ? Wq : (t == 1 ? Wk : Wv)) + (size_t)e * C * C;
    __shared__ float tile[32][33];
    int k0 = blockIdx.y * 32, n0 = blockIdx.x * 32;
    int tc = threadIdx.x & 31, tr = threadIdx.x >> 5;
    #pragma unroll
    for (int i = 0; i < 4; ++i) {
        int r = tr + i * 8;
        tile[r][tc] = W[(size_t)(k0 + r) * C + n0 + tc];
    }
    __syncthreads();
    #pragma unroll
    for (int i = 0; i < 4; ++i) {
        int r = tr + i * 8;
        Wt[(size_t)p * C * C + (size_t)(n0 + r) * C + k0 + tc] = f2bf(tile[tc][r]);
    }
}

__global__ __launch_bounds__(256) void cast_wo_kernel(
    const float* __restrict__ Wo, u16* __restrict__ Wot)
{
    int p = blockIdx.z;
    const float* W = Wo + (size_t)p * C * C;
    __shared__ float tile[32][33];
    int k0 = blockIdx.y * 32, n0 = blockIdx.x * 32;
    int tc = threadIdx.x & 31, tr = threadIdx.x >> 5;
    #pragma unroll
    for (int i = 0; i < 4; ++i) {
        int r = tr + i * 8;
        tile[r][tc] = W[(size_t)(k0 + r) * C + n0 + tc];
    }
    __syncthreads();
    #pragma unroll
    for (int i = 0; i < 4; ++i) {
        int r = tr + i * 8;
        Wot[(size_t)p * C * C + (size_t)(n0 + r) * C + k0 + tc] = f2bf(tile[tc][r]);
    }
}

// ---------------------------------------------------------------- QKV proj MFMA
// 128x128 tile, 256 thr, BK=32, DEPTH-2 triple-buffer: iter kt issues
// stage(kt+2), waits vmcnt(8) (= only tile kt's 4 loads, issued ~2 iters
// ago -> L2/L3 latency fully hidden). Swapped-operand mfma + uint2 epilogue.
__global__ __launch_bounds__(256) void proj_mfma(
    const u16* __restrict__ Xb, const u16* __restrict__ Wt,
    const float* __restrict__ bq, const float* __restrict__ bk,
    const float* __restrict__ bv,
    u16* __restrict__ out)
{
    constexpr int BK = 32;
    constexpr int NT = C / BK;   // 16
    int p = blockIdx.z;
    int e = p / 3, t = p % 3;
    const float* bias = (t == 0 ? bq : (t == 1 ? bk : bv)) + (size_t)e * C;
    u16* Y = out + (size_t)p * S;
    const u16* Wp = Wt + (size_t)p * C * C;

    int m0 = blockIdx.y * 128;
    int n0 = blockIdx.x * 128;

    __shared__ u16 As[3][128 * BK];   // 3 x 8KB
    __shared__ u16 Bs[3][128 * BK];   // 3 x 8KB  -> 48KB total

    int tid  = threadIdx.x;
    int lane = tid & 63;
    int wid  = tid >> 6;
    int wr = wid >> 1, wc = wid & 1;
    int c = lane & 15, gl = lane >> 4;

    f32x4 acc[4][4];   // [nblk][mblk]
    #pragma unroll
    for (int n = 0; n < 4; ++n)
        #pragma unroll
        for (int m = 0; m < 4; ++m)
            acc[n][m] = (f32x4){0.f, 0.f, 0.f, 0.f};

    int rowA = wr * 64 + c;
    int rowB = wc * 64 + c;

    auto stage = [&](int bb, int kt) {
        int k0 = kt * BK;
        #pragma unroll
        for (int it = 0; it < 2; ++it) {
            int base = it * 256 + wid * 64;       // wave-uniform chunk base
            int ch = base + lane;
            int r = ch >> 2, s = ch & 3;
            int r_src = r ^ ((r >> 2) & 1);
            int s_src = s ^ (r_src & 3);
            gload16(Xb + (size_t)(m0 + r_src) * C + k0 + s_src * 8,
                    &As[bb][base * 8]);
        }
        #pragma unroll
        for (int it = 0; it < 2; ++it) {
            int base = it * 256 + wid * 64;
            int ch = base + lane;
            int r = ch >> 2, s = ch & 3;
            int r_src = r ^ ((r >> 2) & 1);
            int s_src = s ^ (r_src & 3);
            gload16(Wp + (size_t)(n0 + r_src) * C + k0 + s_src * 8,
                    &Bs[bb][base * 8]);
        }
    };

    stage(0, 0);
    stage(1, 1);

    int bb = 0;
    for (int kt = 0; kt < NT; ++kt) {
        if (kt + 2 < NT) {
            int s2 = bb + 2 >= 3 ? bb - 1 : bb + 2;
            stage(s2, kt + 2);       // 4 loads; 2 tiles now in flight
            vmcnt8();                // wait only for tile kt's 4 loads
        } else if (kt + 1 < NT) {
            vmcnt4();                // NT-2: only tile NT-1's loads remain
        } else {
            vmcnt0();                // NT-1
        }
        __syncthreads();
        const char* Ab = (const char*)&As[bb][0];
        const char* Bb = (const char*)&Bs[bb][0];
        short8 af[4], bfr[4];
        #pragma unroll
        for (int m = 0; m < 4; ++m) {
            int row = rowA + m * 16;
            af[m] = *reinterpret_cast<const short8*>(
                Ab + ((row * 64 + gl * 16) ^ ((row & 7) << 4)));
        }
        #pragma unroll
        for (int n = 0; n < 4; ++n) {
            int row = rowB + n * 16;
            bfr[n] = *reinterpret_cast<const short8*>(
                Bb + ((row * 64 + gl * 16) ^ ((row & 7) << 4)));
        }
        #pragma unroll
        for (int n = 0; n < 4; ++n)
            #pragma unroll
            for (int m = 0; m < 4; ++m)
                acc[n][m] = __builtin_amdgcn_mfma_f32_16x16x32_bf16(
                    bfr[n], af[m], acc[n][m], 0, 0, 0);
        if (kt + 1 < NT) __syncthreads();   // seal reads before reuse
        bb = bb + 1 >= 3 ? 0 : bb + 1;
    }

    // epilogue: row = m0+wr*64+m*16+c; col = n0+wc*64+n*16+gl*4  (uint2)
    int mrow = m0 + wr * 64 + c;
    int colb = n0 + wc * 64 + gl * 4;
    #pragma unroll
    for (int n = 0; n < 4; ++n) {
        int col = colb + n * 16;
        float4 b4 = *reinterpret_cast<const float4*>(&bias[col]);
        #pragma unroll
        for (int m = 0; m < 4; ++m) {
            int row = mrow + m * 16;
            uint2 v;
            v.x = packbf(acc[n][m][0] + b4.x, acc[n][m][1] + b4.y);
            v.y = packbf(acc[n][m][2] + b4.z, acc[n][m][3] + b4.w);
            *reinterpret_cast<uint2*>(&Y[(size_t)row * C + col]) = v;
        }
    }
}

// ---------------------------------------------------------------- MFMA flash attention
__global__ __launch_bounds__(256) void attn_mfma(
    const u16* __restrict__ qkv,
    const int* __restrict__ indx, const int* __restrict__ expertArr,
    const float* __restrict__ attnw,
    u16* __restrict__ Obuf)
{
    int head = blockIdx.x;
    int slot = blockIdx.y;
    int z    = blockIdx.z;
    int bh   = z >> 1, qh = z & 1;
    int b    = bh >> 3;
    int mi   = bh * KS + slot;
    int src  = indx[mi];
    int e    = expertArr[mi];
    float ak = attnw[mi];
    int qbase = qh * 128;

    const u16* qp = qkv + (size_t)(e * 3 + 0) * S + (size_t)bh * L * C + head * DH;
    const u16* kp = qkv + (size_t)(e * 3 + 1) * S + (size_t)(b * H + src) * L * C + head * DH;
    const u16* vp = qkv + (size_t)(e * 3 + 2) * S + (size_t)(b * H + src) * L * C + head * DH;

    __shared__ u16 Ks[64 * 64];
    __shared__ u16 Vt[64 * 64];
    __shared__ u16 Pl[4][32 * 64];

    int tid = threadIdx.x, lane = tid & 63, w = tid >> 6;
    int c = lane & 15, gl = lane >> 4;
    int qoff = qbase + w * 32;

    short8 qf[2][2];
    #pragma unroll
    for (int n = 0; n < 2; ++n)
        #pragma unroll
        for (int kf = 0; kf < 2; ++kf)
            qf[n][kf] = *reinterpret_cast<const short8*>(
                qp + (size_t)(qoff + n * 16 + c) * C + kf * 32 + 8 * gl);

    f32x4 accO[4][2];
    #pragma unroll
    for (int m = 0; m < 4; ++m)
        #pragma unroll
        for (int n = 0; n < 2; ++n)
            accO[m][n] = (f32x4){0.f, 0.f, 0.f, 0.f};
    float mrun[2], lrun[2];
    #pragma unroll
    for (int n = 0; n < 2; ++n) { mrun[n] = -1e30f; lrun[n] = 0.f; }

    char* Plw = (char*)&Pl[w][0];

    for (int t = 0; t < 4; ++t) {
        int c0 = t * 64;
        __syncthreads();
        #pragma unroll
        for (int it = 0; it < 2; ++it) {
            int ch = tid + 256 * it;
            int r = ch >> 3, cb = ch & 7;
            short8 kv = *reinterpret_cast<const short8*>(kp + (size_t)(c0 + r) * C + cb * 8);
            int ad = (r * 128 + cb * 16) ^ ((r & 7) << 4);
            *reinterpret_cast<short8*>((char*)Ks + ad) = kv;
        }
        {
            int rp = tid & 31;
            int d0 = (tid >> 5) * 8;
            const u16* v0p = vp + (size_t)(c0 + 2 * rp) * C + d0;
            const u16* v1p = v0p + C;
            ushort4 a0 = *reinterpret_cast<const ushort4*>(v0p);
            ushort4 a1 = *reinterpret_cast<const ushort4*>(v0p + 4);
            ushort4 b0 = *reinterpret_cast<const ushort4*>(v1p);
            ushort4 b1 = *reinterpret_cast<const ushort4*>(v1p + 4);
            u16 va[8] = {a0.x, a0.y, a0.z, a0.w, a1.x, a1.y, a1.z, a1.w};
            u16 vb[8] = {b0.x, b0.y, b0.z, b0.w, b1.x, b1.y, b1.z, b1.w};
            #pragma unroll
            for (int j = 0; j < 8; ++j) {
                u32 pk = ((u32)vb[j] << 16) | (u32)va[j];
                int ad = ((d0 + j) * 128 + rp * 4) ^ (((d0 + j) & 7) << 4);
                *reinterpret_cast<u32*>((char*)Vt + ad) = pk;
            }
        }
        __syncthreads();

        f32x4 accS[4][2];
        #pragma unroll
        for (int m = 0; m < 4; ++m)
            #pragma unroll
            for (int n = 0; n < 2; ++n)
                accS[m][n] = (f32x4){0.f, 0.f, 0.f, 0.f};
        #pragma unroll
        for (int kf = 0; kf < 2; ++kf) {
            short8 ka[4];
            #pragma unroll
            for (int m = 0; m < 4; ++m) {
                int row = m * 16 + c;
                ka[m] = *reinterpret_cast<const short8*>(
                    (char*)Ks + ((row * 128 + (kf * 32 + 8 * gl) * 2) ^ ((row & 7) << 4)));
            }
            #pragma unroll
            for (int m = 0; m < 4; ++m)
                #pragma unroll
                for (int n = 0; n < 2; ++n)
                    accS[m][n] = __builtin_amdgcn_mfma_f32_16x16x32_bf16(
                        ka[m], qf[n][kf], accS[m][n], 0, 0, 0);
        }

        #pragma unroll
        for (int n = 0; n < 2; ++n) {
            float tm = -1e30f;
            #pragma unroll
            for (int m = 0; m < 4; ++m)
                #pragma unroll
                for (int r = 0; r < 4; ++r)
                    tm = fmaxf(tm, accS[m][n][r] * 0.125f);
            tm = fmaxf(tm, __shfl_xor(tm, 16));
            tm = fmaxf(tm, __shfl_xor(tm, 32));
            float nm = fmaxf(mrun[n], tm);
            float al = __expf(mrun[n] - nm);
            mrun[n] = nm;
            lrun[n] *= al;
            #pragma unroll
            for (int m = 0; m < 4; ++m)
                #pragma unroll
                for (int r = 0; r < 4; ++r)
                    accO[m][n][r] *= al;
            float ps = 0.f;
            #pragma unroll
            for (int m = 0; m < 4; ++m)
                #pragma unroll
                for (int r = 0; r < 4; ++r) {
                    float pv = __expf(accS[m][n][r] * 0.125f - nm);
                    accS[m][n][r] = pv;
                    ps += pv;
                }
            lrun[n] += ps;
            int row = n * 16 + c;
            int sw = (row & 7) << 4;
            #pragma unroll
            for (int m = 0; m < 4; ++m) {
                u32 p0 = packbf(accS[m][n][0], accS[m][n][1]);
                u32 p1 = packbf(accS[m][n][2], accS[m][n][3]);
                int base = row * 128 + (m * 16 + 4 * gl) * 2;
                *reinterpret_cast<u32*>(Plw + (base ^ sw)) = p0;
                *reinterpret_cast<u32*>(Plw + ((base + 4) ^ sw)) = p1;
            }
        }

        #pragma unroll
        for (int kf = 0; kf < 2; ++kf) {
            short8 va[4], pb[2];
            #pragma unroll
            for (int m = 0; m < 4; ++m) {
                int row = m * 16 + c;
                va[m] = *reinterpret_cast<const short8*>(
                    (char*)Vt + ((row * 128 + (kf * 32 + 8 * gl) * 2) ^ ((row & 7) << 4)));
            }
            #pragma unroll
            for (int n = 0; n < 2; ++n) {
                int row = n * 16 + c;
                pb[n] = *reinterpret_cast<const short8*>(
                    Plw + ((row * 128 + (kf * 32 + 8 * gl) * 2) ^ ((row & 7) << 4)));
            }
            #pragma unroll
            for (int m = 0; m < 4; ++m)
                #pragma unroll
                for (int n = 0; n < 2; ++n)
                    accO[m][n] = __builtin_amdgcn_mfma_f32_16x16x32_bf16(
                        va[m], pb[n], accO[m][n], 0, 0, 0);
        }
    }

    float inv[2];
    #pragma unroll
    for (int n = 0; n < 2; ++n) {
        float lv = lrun[n];
        lv += __shfl_xor(lv, 16);
        lv += __shfl_xor(lv, 32);
        inv[n] = ak / lv;     // fold a_k into O
    }
    #pragma unroll
    for (int m = 0; m < 4; ++m)
        #pragma unroll
        for (int n = 0; n < 2; ++n) {
            int row = n * 16 + c;
            int sw = (row & 7) << 4;
            float o0 = accO[m][n][0] * inv[n];
            float o1 = accO[m][n][1] * inv[n];
            float o2 = accO[m][n][2] * inv[n];
            float o3 = accO[m][n][3] * inv[n];
            int base = row * 128 + (m * 16 + 4 * gl) * 2;
            *reinterpret_cast<u32*>(Plw + (base ^ sw)) = packbf(o0, o1);
            *reinterpret_cast<u32*>(Plw + ((base + 4) ^ sw)) = packbf(o2, o3);
        }
    #pragma unroll
    for (int it = 0; it < 4; ++it) {
        int q = it * 8 + (lane >> 3), cb = lane & 7;
        short8 ov = *reinterpret_cast<const short8*>(
            Plw + ((q * 128 + cb * 16) ^ ((q & 7) << 4)));
        *reinterpret_cast<short8*>(
            Obuf + ((size_t)mi * L + qoff + q) * C + head * DH + cb * 8) = ov;
    }
}

// ---------------------------------------------------------------- Wo fused-K GEMM + ew epilogue
// R9 structure (XCD remap, 64x64) upgraded to DEPTH-2 triple-buffer
// counted-vmcnt pipeline (vmcnt(8)/(4)/(0)); R9 epilogue unchanged.
__global__ __launch_bounds__(256) void wo_fused_ew(
    const u16* __restrict__ Obuf, const u16* __restrict__ Wot,
    const int* __restrict__ expertArr, const float* __restrict__ biasC,
    const float* __restrict__ xin,
    float* __restrict__ xout, u16* __restrict__ XbOut)
{
    constexpr int BK = 64;
    int bid  = blockIdx.x;             // 0..511
    int xcd  = bid & 7;
    int slot = bid >> 3;               // 0..63
    int gwi  = xcd * 64 + slot;
    int bh   = gwi >> 5;
    int wp   = gwi & 31;
    int n0   = (wp & 7) * 64;
    int m0   = (wp >> 3) * 64;

    int e4[KS];
    #pragma unroll
    for (int k = 0; k < KS; ++k) e4[k] = expertArr[bh * KS + k];

    __shared__ u16 As[3][64 * BK];    // 3 x 8KB
    __shared__ u16 Bs[3][64 * BK];    // 3 x 8KB -> 48KB

    int tid = threadIdx.x, lane = tid & 63, wid = tid >> 6;
    int wr = wid >> 1, wc = wid & 1;   // 2x2 waves of 32x32
    int c = lane & 15, gl = lane >> 4;

    f32x4 acc[2][2];
    #pragma unroll
    for (int m = 0; m < 2; ++m)
        #pragma unroll
        for (int n = 0; n < 2; ++n)
            acc[m][n] = (f32x4){0.f, 0.f, 0.f, 0.f};

    auto stage = [&](int bb, int kt) {
        int kslot = kt >> 3;
        int k0    = (kt & 7) * BK;
        const u16* Ap = Obuf + ((size_t)(bh * KS + kslot) * L + m0) * C + k0;
        const u16* Bp = Wot + (size_t)e4[kslot] * C * C + (size_t)n0 * C + k0;
        #pragma unroll
        for (int it = 0; it < 2; ++it) {
            int base = wid * 64 + it * 256;
            int ch = base + lane;
            int r = ch >> 3, cb = ch & 7;
            int ksw = (cb ^ (r & 7)) << 3;
            gload16(Ap + (size_t)r * C + ksw, &As[bb][base * 8]);
        }
        #pragma unroll
        for (int it = 0; it < 2; ++it) {
            int base = wid * 64 + it * 256;
            int ch = base + lane;
            int r = ch >> 3, cb = ch & 7;
            int ksw = (cb ^ (r & 7)) << 3;
            gload16(Bp + (size_t)r * C + ksw, &Bs[bb][base * 8]);
        }
    };

    stage(0, 0);
    stage(1, 1);

    constexpr int NT = 4 * (C / BK);   // 32 k-tiles
    int bb = 0;
    for (int kt = 0; kt < NT; ++kt) {
        if (kt + 2 < NT) {
            int s2 = bb + 2 >= 3 ? bb - 1 : bb + 2;
            stage(s2, kt + 2);
            vmcnt8();                // wait only for tile kt's 4 loads
        } else if (kt + 1 < NT) {
            vmcnt4();
        } else {
            vmcnt0();
        }
        __syncthreads();
        const char* Ab = (const char*)&As[bb][0];
        const char* Bb = (const char*)&Bs[bb][0];
        #pragma unroll
        for (int ks = 0; ks < 2; ++ks) {
            int kb2 = (ks * 32 + 8 * gl) * 2;
            short8 af[2], bfr[2];
            #pragma unroll
            for (int m = 0; m < 2; ++m) {
                int row = wr * 32 + m * 16 + c;
                af[m] = *reinterpret_cast<const short8*>(
                    Ab + ((row * 128 + kb2) ^ ((row & 7) << 4)));
            }
            #pragma unroll
            for (int n = 0; n < 2; ++n) {
                int row = wc * 32 + n * 16 + c;
                bfr[n] = *reinterpret_cast<const short8*>(
                    Bb + ((row * 128 + kb2) ^ ((row & 7) << 4)));
            }
            #pragma unroll
            for (int m = 0; m < 2; ++m)
                #pragma unroll
                for (int n = 0; n < 2; ++n)
                    acc[m][n] = __builtin_amdgcn_mfma_f32_16x16x32_bf16(
                        af[m], bfr[n], acc[m][n], 0, 0, 0);
        }
        if (kt + 1 < NT) __syncthreads();
        bb = bb + 1 >= 3 ? 0 : bb + 1;
    }

    // ---- fused epilogue: +biasC, relu, +residual, store f32 + bf16
    const float* xr = xin + (size_t)bh * L * C;
    float* xo = xout + (size_t)bh * L * C;
    u16*   xb = XbOut + (size_t)bh * L * C;
    float biasS[2];
    #pragma unroll
    for (int n = 0; n < 2; ++n)
        biasS[n] = biasC[(size_t)bh * C + n0 + wc * 32 + n * 16 + c];
    #pragma unroll
    for (int m = 0; m < 2; ++m) {
        #pragma unroll
        for (int r = 0; r < 4; ++r) {
            int row = m0 + wr * 32 + m * 16 + 4 * gl + r;
            #pragma unroll
            for (int n = 0; n < 2; ++n) {
                int col = n0 + wc * 32 + n * 16 + c;
                float v = acc[m][n][r] + biasS[n];
                float o = fmaxf(v, 0.f) + xr[(size_t)row * C + col];
                xo[(size_t)row * C + col] = o;
                xb[(size_t)row * C + col] = f2bf(o);
            }
        }
    }
}

// ----------------------------------------------------------------------------
extern "C" void kernel_launch(void* const* d_in, const int* in_sizes, int n_in,
                              void* d_out, int out_size, void* d_ws, size_t ws_size,
                              hipStream_t stream) {
    const float* gmap = (const float*)d_in[0];
    const float* hist = (const float*)d_in[1];
    const float* cur  = (const float*)d_in[2];
    const float* Wq   = (const float*)d_in[6];
    const float* bq   = (const float*)d_in[7];
    const float* Wk   = (const float*)d_in[8];
    const float* bk   = (const float*)d_in[9];
    const float* Wv   = (const float*)d_in[10];
    const float* bv   = (const float*)d_in[11];
    const float* Wo   = (const float*)d_in[12];
    const float* bo   = (const float*)d_in[13];
    float* outp       = (float*)d_out;

    char* ws = (char*)d_ws;
    float* ctx  = (float*)(ws);                      // [0,4S)
    float* x1   = (float*)(ws + 4 * S);              // [4S,8S)
    u16*   qkv  = (u16*)(ws + 12 * S);               // [12S,30S)
    u16*   Obuf = (u16*)(ws + 30 * S);               // [30S,38S)
    char*  tail = ws + 38 * S;
    float* attnw  = (float*)(tail);                  // 256 B
    int*   indx   = (int*)(tail + 256);
    int*   expert = (int*)(tail + 512);
    float* biasC  = (float*)(tail + 1024);           // 32 KB
    u16*   Wot    = (u16*)(tail + 64 * 1024);        // 1.57 MB
    u16*   Xb     = (u16*)(tail + 2 * 1024 * 1024);  // 4 MB
    u16*   Wt     = (u16*)(tail + 8 * 1024 * 1024);  // 4.7 MB

    dim3 projGrid(C / 128, M4 / 128, 9);             // 4 x 32 x 9 = 1152
    dim3 castWGrid(C / 32, C / 32, 9);
    dim3 castWoGrid(C / 32, C / 32, 3);
    dim3 attnGrid(NH, KS, BH * 2);
    int woBlocks = (C / 64) * (L / 64) * BH;         // 512, flat + remap
    int ewBlocks = (int)(S / 4 / 256);   // 2048

    concat_cast_kernel<<<ewBlocks, 256, 0, stream>>>(hist, cur, ctx, Xb);
    topk_kernel<<<1, 64, 0, stream>>>(gmap, attnw, indx, expert);
    biasc_kernel<<<BH, 256, 0, stream>>>(bo, attnw, expert, biasC);
    cast_wo_kernel<<<castWoGrid, 256, 0, stream>>>(Wo, Wot);
    cast_w_kernel<<<castWGrid, 256, 0, stream>>>(Wq, Wk, Wv, Wt);

    // ---- layer 1: ctx -> x1 (+Xb for layer-2 proj)
    proj_mfma<<<projGrid, 256, 0, stream>>>(Xb, Wt, bq, bk, bv, qkv);
    attn_mfma<<<attnGrid, 256, 0, stream>>>(qkv, indx, expert, attnw, Obuf);
    wo_fused_ew<<<woBlocks, 256, 0, stream>>>(Obuf, Wot, expert, biasC, ctx, x1, Xb);

    // ---- layer 2: x1 -> out
    proj_mfma<<<projGrid, 256, 0, stream>>>(Xb, Wt, bq, bk, bv, qkv);
    attn_mfma<<<attnGrid, 256, 0, stream>>>(qkv, indx, expert, attnw, Obuf);
    wo_fused_ew<<<woBlocks, 256, 0, stream>>>(Obuf, Wot, expert, biasC, x1, outp, Xb);
}

// Round 13
// 173.924 us; speedup vs baseline: 1.2811x; 1.0298x over previous
//
#include <hip/hip_runtime.h>
#include <hip/hip_bf16.h>

// Problem dims
constexpr int B   = 2;
constexpr int HH  = 7;    // history turns
constexpr int H   = 8;    // total turns
constexpr int L   = 256;
constexpr int C   = 512;
constexpr int NH  = 8;
constexpr int DH  = 64;
constexpr int KS  = 4;    // top-k slots
constexpr int BH  = B * H;          // 16
constexpr int M4  = B * H * L;      // 4096 rows
constexpr size_t S = (size_t)B * H * L * C;  // 2,097,152 elems

typedef __attribute__((ext_vector_type(8))) short short8;
typedef __attribute__((ext_vector_type(4))) float f32x4;
typedef unsigned short u16;
typedef unsigned int u32;

__device__ inline float bf2f(u16 u) {
    u32 x = ((u32)u) << 16;
    return __uint_as_float(x);
}
__device__ inline u16 f2bf(float f) {
    __hip_bfloat16 h = __float2bfloat16(f);
    return *reinterpret_cast<u16*>(&h);
}
__device__ inline u32 packbf(float lo, float hi) {
    return ((u32)f2bf(hi) << 16) | (u32)f2bf(lo);
}
__device__ inline void gload16(const void* g, void* l) {
    __builtin_amdgcn_global_load_lds(
        (const __attribute__((address_space(1))) void*)g,
        (__attribute__((address_space(3))) void*)l,
        16, 0, 0);
}
__device__ inline void vmcnt0() {
    asm volatile("s_waitcnt vmcnt(0)" ::: "memory");
}
__device__ inline void vmcnt4() {
    asm volatile("s_waitcnt vmcnt(4)" ::: "memory");
}

// ------------------------------------------------- concat ctx (+bf16 cast)
__global__ __launch_bounds__(256) void concat_cast_kernel(
    const float* __restrict__ hist, const float* __restrict__ cur,
    float* __restrict__ ctx, u16* __restrict__ Xb)
{
    size_t i4 = (size_t)blockIdx.x * 256 + threadIdx.x;
    size_t elem = i4 * 4;
    int c  = (int)(elem & (C - 1));
    size_t rest = elem >> 9;
    int l  = (int)(rest & (L - 1));
    int bh = (int)(rest >> 8);
    int h  = bh & (H - 1);
    int b  = bh >> 3;
    float4 v;
    if (h < HH) {
        size_t off = ((((size_t)b * HH + h) * L + l) * C + c);
        v = *reinterpret_cast<const float4*>(hist + off);
    } else {
        size_t off = (((size_t)b * L + l) * C + c);
        v = *reinterpret_cast<const float4*>(cur + off);
    }
    *reinterpret_cast<float4*>(ctx + elem) = v;
    ushort4 o;
    o.x = f2bf(v.x); o.y = f2bf(v.y); o.z = f2bf(v.z); o.w = f2bf(v.w);
    *reinterpret_cast<ushort4*>(Xb + elem) = o;
}

// ---------------------------------------------------------------- topk+softmax
__global__ void topk_kernel(const float* __restrict__ gmap,
                            float* __restrict__ attnw,
                            int* __restrict__ indxO,
                            int* __restrict__ expertO)
{
    int t = threadIdx.x;
    if (t >= BH) return;
    int h = t & (H - 1);
    const float* row = gmap + (size_t)t * H;
    float v[H];
    #pragma unroll
    for (int j = 0; j < H; ++j) v[j] = row[j];
    float sel[KS]; int si[KS];
    #pragma unroll
    for (int kk = 0; kk < KS; ++kk) {
        float best = -1e30f; int bi = 0;
        #pragma unroll
        for (int j = 0; j < H; ++j) {
            if (v[j] > best) { best = v[j]; bi = j; }
        }
        sel[kk] = best; si[kk] = bi; v[bi] = -1e30f;
    }
    float mx = sel[0];
    float w[KS]; float sum = 0.f;
    #pragma unroll
    for (int kk = 0; kk < KS; ++kk) { w[kk] = __expf(sel[kk] - mx); sum += w[kk]; }
    float inv = 1.f / sum;
    #pragma unroll
    for (int kk = 0; kk < KS; ++kk) {
        attnw[t * KS + kk] = w[kk] * inv;
        indxO[t * KS + kk] = si[kk];
        int e = (si[kk] == h) ? 0 : ((si[kk] > h) ? 2 : 1);
        expertO[t * KS + kk] = e;
    }
}

// ---------------------------------------------------------------- combined bias
__global__ __launch_bounds__(256) void biasc_kernel(
    const float* __restrict__ bo,
    const float* __restrict__ attnw, const int* __restrict__ expertArr,
    float* __restrict__ biasC)
{
    int bh = blockIdx.x;
    float a[KS]; int e[KS];
    #pragma unroll
    for (int k = 0; k < KS; ++k) {
        a[k] = attnw[bh * KS + k];
        e[k] = expertArr[bh * KS + k];
    }
    #pragma unroll
    for (int it = 0; it < 2; ++it) {
        int c = threadIdx.x + it * 256;
        float s = 0.f;
        #pragma unroll
        for (int k = 0; k < KS; ++k)
            s += a[k] * bo[(size_t)e[k] * C + c];
        biasC[(size_t)bh * C + c] = s;
    }
}

// ---------------------------------------------------------------- weight casts
__global__ __launch_bounds__(256) void cast_w_kernel(
    const float* __restrict__ Wq, const float* __restrict__ Wk,
    const float* __restrict__ Wv, u16* __restrict__ Wt)
{
    int p = blockIdx.z;
    int e = p / 3, t = p % 3;
    const float* W = (t == 0 ? Wq : (t == 1 ? Wk : Wv)) + (size_t)e * C * C;
    __shared__ float tile[32][33];
    int k0 = blockIdx.y * 32, n0 = blockIdx.x * 32;
    int tc = threadIdx.x & 31, tr = threadIdx.x >> 5;
    #pragma unroll
    for (int i = 0; i < 4; ++i) {
        int r = tr + i * 8;
        tile[r][tc] = W[(size_t)(k0 + r) * C + n0 + tc];
    }
    __syncthreads();
    #pragma unroll
    for (int i = 0; i < 4; ++i) {
        int r = tr + i * 8;
        Wt[(size_t)p * C * C + (size_t)(n0 + r) * C + k0 + tc] = f2bf(tile[tc][r]);
    }
}

__global__ __launch_bounds__(256) void cast_wo_kernel(
    const float* __restrict__ Wo, u16* __restrict__ Wot)
{
    int p = blockIdx.z;
    const float* W = Wo + (size_t)p * C * C;
    __shared__ float tile[32][33];
    int k0 = blockIdx.y * 32, n0 = blockIdx.x * 32;
    int tc = threadIdx.x & 31, tr = threadIdx.x >> 5;
    #pragma unroll
    for (int i = 0; i < 4; ++i) {
        int r = tr + i * 8;
        tile[r][tc] = W[(size_t)(k0 + r) * C + n0 + tc];
    }
    __syncthreads();
    #pragma unroll
    for (int i = 0; i < 4; ++i) {
        int r = tr + i * 8;
        Wot[(size_t)p * C * C + (size_t)(n0 + r) * C + k0 + tc] = f2bf(tile[tc][r]);
    }
}

// ---------------------------------------------------------------- QKV proj MFMA
// R9 best-measured config: BK=32 dbuf + counted vmcnt(4), XCD-flat grid
// remap, swizzled LDS via pre-swizzled global source.
__global__ __launch_bounds__(256) void proj_mfma(
    const u16* __restrict__ Xb, const u16* __restrict__ Wt,
    const float* __restrict__ bq, const float* __restrict__ bk,
    const float* __restrict__ bv,
    u16* __restrict__ out)
{
    constexpr int BK = 32;
    constexpr int NT = C / BK;   // 16
    int bid  = blockIdx.x;            // 0..1151
    int xcd  = bid & 7;
    int slot = bid >> 3;              // 0..143
    int gwi  = xcd * 144 + slot;
    int p    = gwi >> 7;              // /128 -> plane
    int wp   = gwi & 127;
    int n0   = (wp & 3) * 128;
    int m0   = (wp >> 2) * 128;

    int e = p / 3, t = p % 3;
    const float* bias = (t == 0 ? bq : (t == 1 ? bk : bv)) + (size_t)e * C;
    u16* Y = out + (size_t)p * S;
    const u16* Wp = Wt + (size_t)p * C * C;

    __shared__ u16 As[2][128 * BK];   // 2 x 8KB
    __shared__ u16 Bs[2][128 * BK];   // 2 x 8KB

    int tid  = threadIdx.x;
    int lane = tid & 63;
    int wid  = tid >> 6;
    int wr = wid >> 1, wc = wid & 1;
    int c = lane & 15, gl = lane >> 4;

    f32x4 acc[4][4];
    #pragma unroll
    for (int m = 0; m < 4; ++m)
        #pragma unroll
        for (int n = 0; n < 4; ++n)
            acc[m][n] = (f32x4){0.f, 0.f, 0.f, 0.f};

    int rowA = wr * 64 + c;
    int rowB = wc * 64 + c;

    auto stage = [&](int bb, int kt) {
        int k0 = kt * BK;
        #pragma unroll
        for (int it = 0; it < 2; ++it) {
            int base = it * 256 + wid * 64;       // wave-uniform chunk base
            int ch = base + lane;
            int r = ch >> 2, s = ch & 3;
            int r_src = r ^ ((r >> 2) & 1);
            int s_src = s ^ (r_src & 3);
            gload16(Xb + (size_t)(m0 + r_src) * C + k0 + s_src * 8,
                    &As[bb][base * 8]);
        }
        #pragma unroll
        for (int it = 0; it < 2; ++it) {
            int base = it * 256 + wid * 64;
            int ch = base + lane;
            int r = ch >> 2, s = ch & 3;
            int r_src = r ^ ((r >> 2) & 1);
            int s_src = s ^ (r_src & 3);
            gload16(Wp + (size_t)(n0 + r_src) * C + k0 + s_src * 8,
                    &Bs[bb][base * 8]);
        }
    };

    stage(0, 0);

    for (int kt = 0; kt < NT; ++kt) {
        int bb = kt & 1;
        if (kt + 1 < NT) {
            stage(bb ^ 1, kt + 1);   // 4 loads -> in flight across barriers
            vmcnt4();                // wait only for tile kt's 4 loads
        } else {
            vmcnt0();
        }
        __syncthreads();
        const char* Ab = (const char*)&As[bb][0];
        const char* Bb = (const char*)&Bs[bb][0];
        short8 af[4], bfr[4];
        #pragma unroll
        for (int m = 0; m < 4; ++m) {
            int row = rowA + m * 16;
            af[m] = *reinterpret_cast<const short8*>(
                Ab + ((row * 64 + gl * 16) ^ ((row & 7) << 4)));
        }
        #pragma unroll
        for (int n = 0; n < 4; ++n) {
            int row = rowB + n * 16;
            bfr[n] = *reinterpret_cast<const short8*>(
                Bb + ((row * 64 + gl * 16) ^ ((row & 7) << 4)));
        }
        #pragma unroll
        for (int m = 0; m < 4; ++m)
            #pragma unroll
            for (int n = 0; n < 4; ++n)
                acc[m][n] = __builtin_amdgcn_mfma_f32_16x16x32_bf16(
                    af[m], bfr[n], acc[m][n], 0, 0, 0);
        if (kt + 1 < NT) __syncthreads();   // seal reads before next stage overwrites
    }

    int colb = n0 + wc * 64 + c;
    int rowb = m0 + wr * 64 + gl * 4;
    #pragma unroll
    for (int n = 0; n < 4; ++n) {
        int col = colb + n * 16;
        float bcol = bias[col];
        #pragma unroll
        for (int m = 0; m < 4; ++m) {
            #pragma unroll
            for (int r = 0; r < 4; ++r) {
                int row = rowb + m * 16 + r;
                Y[(size_t)row * C + col] = f2bf(acc[m][n][r] + bcol);
            }
        }
    }
}

// ---------------------------------------------------------------- MFMA flash attention
__global__ __launch_bounds__(256) void attn_mfma(
    const u16* __restrict__ qkv,
    const int* __restrict__ indx, const int* __restrict__ expertArr,
    const float* __restrict__ attnw,
    u16* __restrict__ Obuf)
{
    int head = blockIdx.x;
    int slot = blockIdx.y;
    int z    = blockIdx.z;
    int bh   = z >> 1, qh = z & 1;
    int b    = bh >> 3;
    int mi   = bh * KS + slot;
    int src  = indx[mi];
    int e    = expertArr[mi];
    float ak = attnw[mi];
    int qbase = qh * 128;

    const u16* qp = qkv + (size_t)(e * 3 + 0) * S + (size_t)bh * L * C + head * DH;
    const u16* kp = qkv + (size_t)(e * 3 + 1) * S + (size_t)(b * H + src) * L * C + head * DH;
    const u16* vp = qkv + (size_t)(e * 3 + 2) * S + (size_t)(b * H + src) * L * C + head * DH;

    __shared__ u16 Ks[64 * 64];
    __shared__ u16 Vt[64 * 64];
    __shared__ u16 Pl[4][32 * 64];

    int tid = threadIdx.x, lane = tid & 63, w = tid >> 6;
    int c = lane & 15, gl = lane >> 4;
    int qoff = qbase + w * 32;

    short8 qf[2][2];
    #pragma unroll
    for (int n = 0; n < 2; ++n)
        #pragma unroll
        for (int kf = 0; kf < 2; ++kf)
            qf[n][kf] = *reinterpret_cast<const short8*>(
                qp + (size_t)(qoff + n * 16 + c) * C + kf * 32 + 8 * gl);

    f32x4 accO[4][2];
    #pragma unroll
    for (int m = 0; m < 4; ++m)
        #pragma unroll
        for (int n = 0; n < 2; ++n)
            accO[m][n] = (f32x4){0.f, 0.f, 0.f, 0.f};
    float mrun[2], lrun[2];
    #pragma unroll
    for (int n = 0; n < 2; ++n) { mrun[n] = -1e30f; lrun[n] = 0.f; }

    char* Plw = (char*)&Pl[w][0];

    for (int t = 0; t < 4; ++t) {
        int c0 = t * 64;
        __syncthreads();
        #pragma unroll
        for (int it = 0; it < 2; ++it) {
            int ch = tid + 256 * it;
            int r = ch >> 3, cb = ch & 7;
            short8 kv = *reinterpret_cast<const short8*>(kp + (size_t)(c0 + r) * C + cb * 8);
            int ad = (r * 128 + cb * 16) ^ ((r & 7) << 4);
            *reinterpret_cast<short8*>((char*)Ks + ad) = kv;
        }
        {
            int rp = tid & 31;
            int d0 = (tid >> 5) * 8;
            const u16* v0p = vp + (size_t)(c0 + 2 * rp) * C + d0;
            const u16* v1p = v0p + C;
            ushort4 a0 = *reinterpret_cast<const ushort4*>(v0p);
            ushort4 a1 = *reinterpret_cast<const ushort4*>(v0p + 4);
            ushort4 b0 = *reinterpret_cast<const ushort4*>(v1p);
            ushort4 b1 = *reinterpret_cast<const ushort4*>(v1p + 4);
            u16 va[8] = {a0.x, a0.y, a0.z, a0.w, a1.x, a1.y, a1.z, a1.w};
            u16 vb[8] = {b0.x, b0.y, b0.z, b0.w, b1.x, b1.y, b1.z, b1.w};
            #pragma unroll
            for (int j = 0; j < 8; ++j) {
                u32 pk = ((u32)vb[j] << 16) | (u32)va[j];
                int ad = ((d0 + j) * 128 + rp * 4) ^ (((d0 + j) & 7) << 4);
                *reinterpret_cast<u32*>((char*)Vt + ad) = pk;
            }
        }
        __syncthreads();

        f32x4 accS[4][2];
        #pragma unroll
        for (int m = 0; m < 4; ++m)
            #pragma unroll
            for (int n = 0; n < 2; ++n)
                accS[m][n] = (f32x4){0.f, 0.f, 0.f, 0.f};
        #pragma unroll
        for (int kf = 0; kf < 2; ++kf) {
            short8 ka[4];
            #pragma unroll
            for (int m = 0; m < 4; ++m) {
                int row = m * 16 + c;
                ka[m] = *reinterpret_cast<const short8*>(
                    (char*)Ks + ((row * 128 + (kf * 32 + 8 * gl) * 2) ^ ((row & 7) << 4)));
            }
            #pragma unroll
            for (int m = 0; m < 4; ++m)
                #pragma unroll
                for (int n = 0; n < 2; ++n)
                    accS[m][n] = __builtin_amdgcn_mfma_f32_16x16x32_bf16(
                        ka[m], qf[n][kf], accS[m][n], 0, 0, 0);
        }

        #pragma unroll
        for (int n = 0; n < 2; ++n) {
            float tm = -1e30f;
            #pragma unroll
            for (int m = 0; m < 4; ++m)
                #pragma unroll
                for (int r = 0; r < 4; ++r)
                    tm = fmaxf(tm, accS[m][n][r] * 0.125f);
            tm = fmaxf(tm, __shfl_xor(tm, 16));
            tm = fmaxf(tm, __shfl_xor(tm, 32));
            float nm = fmaxf(mrun[n], tm);
            float al = __expf(mrun[n] - nm);
            mrun[n] = nm;
            lrun[n] *= al;
            #pragma unroll
            for (int m = 0; m < 4; ++m)
                #pragma unroll
                for (int r = 0; r < 4; ++r)
                    accO[m][n][r] *= al;
            float ps = 0.f;
            #pragma unroll
            for (int m = 0; m < 4; ++m)
                #pragma unroll
                for (int r = 0; r < 4; ++r) {
                    float pv = __expf(accS[m][n][r] * 0.125f - nm);
                    accS[m][n][r] = pv;
                    ps += pv;
                }
            lrun[n] += ps;
            int row = n * 16 + c;
            int sw = (row & 7) << 4;
            #pragma unroll
            for (int m = 0; m < 4; ++m) {
                u32 p0 = packbf(accS[m][n][0], accS[m][n][1]);
                u32 p1 = packbf(accS[m][n][2], accS[m][n][3]);
                int base = row * 128 + (m * 16 + 4 * gl) * 2;
                *reinterpret_cast<u32*>(Plw + (base ^ sw)) = p0;
                *reinterpret_cast<u32*>(Plw + ((base + 4) ^ sw)) = p1;
            }
        }

        #pragma unroll
        for (int kf = 0; kf < 2; ++kf) {
            short8 va[4], pb[2];
            #pragma unroll
            for (int m = 0; m < 4; ++m) {
                int row = m * 16 + c;
                va[m] = *reinterpret_cast<const short8*>(
                    (char*)Vt + ((row * 128 + (kf * 32 + 8 * gl) * 2) ^ ((row & 7) << 4)));
            }
            #pragma unroll
            for (int n = 0; n < 2; ++n) {
                int row = n * 16 + c;
                pb[n] = *reinterpret_cast<const short8*>(
                    Plw + ((row * 128 + (kf * 32 + 8 * gl) * 2) ^ ((row & 7) << 4)));
            }
            #pragma unroll
            for (int m = 0; m < 4; ++m)
                #pragma unroll
                for (int n = 0; n < 2; ++n)
                    accO[m][n] = __builtin_amdgcn_mfma_f32_16x16x32_bf16(
                        va[m], pb[n], accO[m][n], 0, 0, 0);
        }
    }

    float inv[2];
    #pragma unroll
    for (int n = 0; n < 2; ++n) {
        float lv = lrun[n];
        lv += __shfl_xor(lv, 16);
        lv += __shfl_xor(lv, 32);
        inv[n] = ak / lv;     // fold a_k into O
    }
    #pragma unroll
    for (int m = 0; m < 4; ++m)
        #pragma unroll
        for (int n = 0; n < 2; ++n) {
            int row = n * 16 + c;
            int sw = (row & 7) << 4;
            float o0 = accO[m][n][0] * inv[n];
            float o1 = accO[m][n][1] * inv[n];
            float o2 = accO[m][n][2] * inv[n];
            float o3 = accO[m][n][3] * inv[n];
            int base = row * 128 + (m * 16 + 4 * gl) * 2;
            *reinterpret_cast<u32*>(Plw + (base ^ sw)) = packbf(o0, o1);
            *reinterpret_cast<u32*>(Plw + ((base + 4) ^ sw)) = packbf(o2, o3);
        }
    #pragma unroll
    for (int it = 0; it < 4; ++it) {
        int q = it * 8 + (lane >> 3), cb = lane & 7;
        short8 ov = *reinterpret_cast<const short8*>(
            Plw + ((q * 128 + cb * 16) ^ ((q & 7) << 4)));
        *reinterpret_cast<short8*>(
            Obuf + ((size_t)mi * L + qoff + q) * C + head * DH + cb * 8) = ov;
    }
}

// ---------------------------------------------------------------- Wo fused-K GEMM + ew epilogue
// 64x64 tiles, counted vmcnt pipeline, + XCD-locality remap: XCD x gets
// gwi = x*64..x*64+63 -> 2 bh per XCD (Obuf 2MB + Wot 1.5MB fits L2).
__global__ __launch_bounds__(256) void wo_fused_ew(
    const u16* __restrict__ Obuf, const u16* __restrict__ Wot,
    const int* __restrict__ expertArr, const float* __restrict__ biasC,
    const float* __restrict__ xin,
    float* __restrict__ xout, u16* __restrict__ XbOut)
{
    constexpr int BK = 64;
    int bid  = blockIdx.x;             // 0..511
    int xcd  = bid & 7;
    int slot = bid >> 3;               // 0..63
    int gwi  = xcd * 64 + slot;
    int bh   = gwi >> 5;
    int wp   = gwi & 31;
    int n0   = (wp & 7) * 64;
    int m0   = (wp >> 3) * 64;

    int e4[KS];
    #pragma unroll
    for (int k = 0; k < KS; ++k) e4[k] = expertArr[bh * KS + k];

    __shared__ u16 As[2][64 * BK];    // 2 x 8KB
    __shared__ u16 Bs[2][64 * BK];    // 2 x 8KB

    int tid = threadIdx.x, lane = tid & 63, wid = tid >> 6;
    int wr = wid >> 1, wc = wid & 1;   // 2x2 waves of 32x32
    int c = lane & 15, gl = lane >> 4;

    f32x4 acc[2][2];
    #pragma unroll
    for (int m = 0; m < 2; ++m)
        #pragma unroll
        for (int n = 0; n < 2; ++n)
            acc[m][n] = (f32x4){0.f, 0.f, 0.f, 0.f};

    auto stage = [&](int bb, int kt) {
        int kslot = kt >> 3;
        int k0    = (kt & 7) * BK;
        const u16* Ap = Obuf + ((size_t)(bh * KS + kslot) * L + m0) * C + k0;
        const u16* Bp = Wot + (size_t)e4[kslot] * C * C + (size_t)n0 * C + k0;
        #pragma unroll
        for (int it = 0; it < 2; ++it) {
            int base = wid * 64 + it * 256;
            int ch = base + lane;
            int r = ch >> 3, cb = ch & 7;
            int ksw = (cb ^ (r & 7)) << 3;
            gload16(Ap + (size_t)r * C + ksw, &As[bb][base * 8]);
        }
        #pragma unroll
        for (int it = 0; it < 2; ++it) {
            int base = wid * 64 + it * 256;
            int ch = base + lane;
            int r = ch >> 3, cb = ch & 7;
            int ksw = (cb ^ (r & 7)) << 3;
            gload16(Bp + (size_t)r * C + ksw, &Bs[bb][base * 8]);
        }
    };

    stage(0, 0);

    constexpr int NT = 4 * (C / BK);   // 32 k-tiles
    for (int kt = 0; kt < NT; ++kt) {
        int bb = kt & 1;
        if (kt + 1 < NT) {
            stage(bb ^ 1, kt + 1);
            vmcnt4();                // wait for tile kt only
        } else {
            vmcnt0();
        }
        __syncthreads();
        const char* Ab = (const char*)&As[bb][0];
        const char* Bb = (const char*)&Bs[bb][0];
        #pragma unroll
        for (int ks = 0; ks < 2; ++ks) {
            int kb2 = (ks * 32 + 8 * gl) * 2;
            short8 af[2], bfr[2];
            #pragma unroll
            for (int m = 0; m < 2; ++m) {
                int row = wr * 32 + m * 16 + c;
                af[m] = *reinterpret_cast<const short8*>(
                    Ab + ((row * 128 + kb2) ^ ((row & 7) << 4)));
            }
            #pragma unroll
            for (int n = 0; n < 2; ++n) {
                int row = wc * 32 + n * 16 + c;
                bfr[n] = *reinterpret_cast<const short8*>(
                    Bb + ((row * 128 + kb2) ^ ((row & 7) << 4)));
            }
            #pragma unroll
            for (int m = 0; m < 2; ++m)
                #pragma unroll
                for (int n = 0; n < 2; ++n)
                    acc[m][n] = __builtin_amdgcn_mfma_f32_16x16x32_bf16(
                        af[m], bfr[n], acc[m][n], 0, 0, 0);
        }
        if (kt + 1 < NT) __syncthreads();
    }

    // ---- fused epilogue: +biasC, relu, +residual, store f32 + bf16
    const float* xr = xin + (size_t)bh * L * C;
    float* xo = xout + (size_t)bh * L * C;
    u16*   xb = XbOut + (size_t)bh * L * C;
    float biasS[2];
    #pragma unroll
    for (int n = 0; n < 2; ++n)
        biasS[n] = biasC[(size_t)bh * C + n0 + wc * 32 + n * 16 + c];
    #pragma unroll
    for (int m = 0; m < 2; ++m) {
        #pragma unroll
        for (int r = 0; r < 4; ++r) {
            int row = m0 + wr * 32 + m * 16 + 4 * gl + r;
            #pragma unroll
            for (int n = 0; n < 2; ++n) {
                int col = n0 + wc * 32 + n * 16 + c;
                float v = acc[m][n][r] + biasS[n];
                float o = fmaxf(v, 0.f) + xr[(size_t)row * C + col];
                xo[(size_t)row * C + col] = o;
                xb[(size_t)row * C + col] = f2bf(o);
            }
        }
    }
}

// ----------------------------------------------------------------------------
extern "C" void kernel_launch(void* const* d_in, const int* in_sizes, int n_in,
                              void* d_out, int out_size, void* d_ws, size_t ws_size,
                              hipStream_t stream) {
    const float* gmap = (const float*)d_in[0];
    const float* hist = (const float*)d_in[1];
    const float* cur  = (const float*)d_in[2];
    const float* Wq   = (const float*)d_in[6];
    const float* bq   = (const float*)d_in[7];
    const float* Wk   = (const float*)d_in[8];
    const float* bk   = (const float*)d_in[9];
    const float* Wv   = (const float*)d_in[10];
    const float* bv   = (const float*)d_in[11];
    const float* Wo   = (const float*)d_in[12];
    const float* bo   = (const float*)d_in[13];
    float* outp       = (float*)d_out;

    char* ws = (char*)d_ws;
    float* ctx  = (float*)(ws);                      // [0,4S)
    float* x1   = (float*)(ws + 4 * S);              // [4S,8S)
    u16*   qkv  = (u16*)(ws + 12 * S);               // [12S,30S)
    u16*   Obuf = (u16*)(ws + 30 * S);               // [30S,38S)
    char*  tail = ws + 38 * S;
    float* attnw  = (float*)(tail);                  // 256 B
    int*   indx   = (int*)(tail + 256);
    int*   expert = (int*)(tail + 512);
    float* biasC  = (float*)(tail + 1024);           // 32 KB
    u16*   Wot    = (u16*)(tail + 64 * 1024);        // 1.57 MB
    u16*   Xb     = (u16*)(tail + 2 * 1024 * 1024);  // 4 MB
    u16*   Wt     = (u16*)(tail + 8 * 1024 * 1024);  // 4.7 MB

    dim3 castWGrid(C / 32, C / 32, 9);
    dim3 castWoGrid(C / 32, C / 32, 3);
    dim3 attnGrid(NH, KS, BH * 2);
    int projBlocks = (C / 128) * (M4 / 128) * 9;     // 1152, flat + remap
    int woBlocks   = (C / 64) * (L / 64) * BH;       // 512, flat + remap
    int ewBlocks = (int)(S / 4 / 256);   // 2048

    concat_cast_kernel<<<ewBlocks, 256, 0, stream>>>(hist, cur, ctx, Xb);
    topk_kernel<<<1, 64, 0, stream>>>(gmap, attnw, indx, expert);
    biasc_kernel<<<BH, 256, 0, stream>>>(bo, attnw, expert, biasC);
    cast_wo_kernel<<<castWoGrid, 256, 0, stream>>>(Wo, Wot);
    cast_w_kernel<<<castWGrid, 256, 0, stream>>>(Wq, Wk, Wv, Wt);

    // ---- layer 1: ctx -> x1 (+Xb for layer-2 proj)
    proj_mfma<<<projBlocks, 256, 0, stream>>>(Xb, Wt, bq, bk, bv, qkv);
    attn_mfma<<<attnGrid, 256, 0, stream>>>(qkv, indx, expert, attnw, Obuf);
    wo_fused_ew<<<woBlocks, 256, 0, stream>>>(Obuf, Wot, expert, biasC, ctx, x1, Xb);

    // ---- layer 2: x1 -> out
    proj_mfma<<<projBlocks, 256, 0, stream>>>(Xb, Wt, bq, bk, bv, qkv);
    attn_mfma<<<attnGrid, 256, 0, stream>>>(qkv, indx, expert, attnw, Obuf);
    wo_fused_ew<<<woBlocks, 256, 0, stream>>>(Obuf, Wot, expert, biasC, x1, outp, Xb);
}